// Round 10
// baseline (1602.045 us; speedup 1.0000x reference)
//
#include <hip/hip_runtime.h>
#include <hip/hip_fp16.h>

// ---------------------------------------------------------------------------
// 2-layer GCN, fp32 in/out.  out = b2 + A_hat( relu( A_hat(x@W1) + b1 ) @ W2 )
// A_hat = D^-1/2 (A + I) D^-1/2.
// Round 18: CSR DELETED.  R17 counters: binA 90% idle; the binB sort +
// ecsr traffic + agg1f row reads exist only to organize a gather we can do
// directly.  A bucket's full fp32 accumulator (512 nodes x 64 feats = 128KB)
// fits in LDS, so:
//   k_agg1d : one block/bucket streams the bucket's partition edges, gathers
//             xw2f[src] (same fabric-limited gather as old agg1f) and
//             ds_add_f32 into acc[dlow][lane] (64 consecutive floats/wave =
//             conflict-free, fire-and-forget).  Epilogue = relu+b1+W2 dot.
//   k_agg2d : same with scalar acc2[512] (2KB) over g.
//   k_scale : binB minus the sort — wsum histogram + dinv + xw2 dinv-fold
//             (the only cross-bucket dependency, must precede gathers).
// binA_gemm (fused binning + raw MFMA gemm) unchanged from R17.
// Numerics: LDS fp32 atomic order varies per replay ~1e-7 << 1.5e-3 thresh.
// ---------------------------------------------------------------------------

#define NPB_LOG 9
#define NPB     512                  // nodes per coarse bucket
#define PCAP    17408                // mean 16384 + 8 sigma (P_ovf ~1e-13)
#define NEDG    8192                 // edges per binA block
#define GPAD    16                   // gcur stride in ints (64B line)
#define XPAD    136

typedef _Float16 f16x8 __attribute__((ext_vector_type(8)));
typedef float    f32x4 __attribute__((ext_vector_type(4)));

__global__ void k_initcur(int* __restrict__ gcur, int npart) {
    int i = blockIdx.x * blockDim.x + threadIdx.x;
    if (i < npart) gcur[i * GPAD] = i * PCAP;
}

// Fused: blocks [0,nA) = binA edge binning; blocks [nA,nA+nG) = raw GEMM
// xw2_raw[r,64] = fp16( x[r,128] @ W1[128,64] )   (dinv folded by k_scale).
__global__ __launch_bounds__(256) void k_binA_gemm(
        const int* __restrict__ src, const int* __restrict__ dst,
        const float* __restrict__ ea, int* __restrict__ gcur,
        uint2* __restrict__ part,
        const float* __restrict__ x, const float* __restrict__ W1,
        __half* __restrict__ xw2,
        int E, int npart, int nA, int n) {
    __shared__ __align__(16) unsigned char smem[76800];
    int t = threadIdx.x;

    if (blockIdx.x >= nA) {
        // ---------------- GEMM path ----------------
        _Float16* xs = (_Float16*)smem;            // 64*XPAD halves
        _Float16* wt = xs + 64 * XPAD;             // 64*XPAD halves
        int row0 = (blockIdx.x - nA) * 64;
        for (int i = t; i < 64 * 32; i += 256) {
            int r = i >> 5, k4 = i & 31;
            float4 f = make_float4(0.f, 0.f, 0.f, 0.f);
            int gr = row0 + r;
            if (gr < n) f = ((const float4*)x)[(size_t)gr * 32 + k4];
            union { _Float16 h[4]; uint2 u; } tmp;
            tmp.h[0] = (_Float16)f.x; tmp.h[1] = (_Float16)f.y;
            tmp.h[2] = (_Float16)f.z; tmp.h[3] = (_Float16)f.w;
            *(uint2*)&xs[r * XPAD + k4 * 4] = tmp.u;
        }
        for (int i = t; i < 128 * 64; i += 256) {
            int k = i >> 6, nn = i & 63;
            wt[nn * XPAD + k] = (_Float16)W1[i];
        }
        __syncthreads();
        int strip = t >> 6;
        int lane  = t & 63;
        int quad  = lane >> 4;
        int m     = lane & 15;
        f32x4 acc[4] = {{0,0,0,0},{0,0,0,0},{0,0,0,0},{0,0,0,0}};
#pragma unroll
        for (int kc = 0; kc < 4; ++kc) {
            f16x8 a = *(const f16x8*)&xs[(strip * 16 + m) * XPAD + kc * 32 + quad * 8];
#pragma unroll
            for (int nt = 0; nt < 4; ++nt) {
                f16x8 b = *(const f16x8*)&wt[(nt * 16 + m) * XPAD + kc * 32 + quad * 8];
                acc[nt] = __builtin_amdgcn_mfma_f32_16x16x32_f16(a, b, acc[nt], 0, 0, 0);
            }
        }
#pragma unroll
        for (int nt = 0; nt < 4; ++nt) {
#pragma unroll
            for (int reg = 0; reg < 4; ++reg) {
                int gr = row0 + strip * 16 + quad * 4 + reg;
                if (gr < n)
                    xw2[(size_t)gr * 64 + nt * 16 + m] = __float2half(acc[nt][reg]);
            }
        }
        return;
    }

    // ---------------- binA path (R9-verified structure) ----------------
    uint2*         stag  = (uint2*)smem;                   // 64 KB
    unsigned char* stagb = smem + 65536;                   // 8 KB
    int*           hist  = (int*)(smem + 73728);           // 1 KB
    int*           lofs  = hist + 256;                     // 1 KB
    int*           base  = lofs + 256;                     // 1 KB
    int c0 = blockIdx.x * NEDG;
    hist[t] = 0;
    __syncthreads();
    // pass 1: histogram
    for (int j = t; j < NEDG; j += 256) {
        int e = c0 + j;
        if (e < E) atomicAdd(&hist[dst[e] >> NPB_LOG], 1);
    }
    __syncthreads();
    // Kogge-Stone scan over 256 entries -> exclusive offsets; reserve global
    int v = hist[t];
    lofs[t] = v;
    __syncthreads();
    for (int off = 1; off < 256; off <<= 1) {
        int u = (t >= off) ? lofs[t - off] : 0;
        __syncthreads();
        lofs[t] += u;
        __syncthreads();
    }
    int excl = lofs[t] - v;
    if (t < npart && v > 0) base[t] = atomicAdd(&gcur[t * GPAD], v);
    __syncthreads();
    lofs[t] = excl;
    hist[t] = excl;               // reuse as intra-block scatter cursor
    __syncthreads();
    // pass 2: scatter into LDS staging in bucket order
    for (int j = t; j < NEDG; j += 256) {
        int e = c0 + j;
        if (e < E) {
            int d = dst[e];
            int b = d >> NPB_LOG;
            int p = atomicAdd(&hist[b], 1);
            stag[p]  = make_uint2((uint)src[e] | ((uint)(d & (NPB - 1)) << 17),
                                  __float_as_uint(ea[e]));
            stagb[p] = (unsigned char)b;
        }
    }
    __syncthreads();
    // pass 3: flush — consecutive slots in a bucket -> consecutive global addrs
    int nvalid = min(NEDG, E - c0);
    for (int j = t; j < nvalid; j += 256) {
        int b = stagb[j];
        int gp = base[b] + (j - lofs[b]);
        if (gp < (b + 1) * PCAP) part[gp] = stag[j];
    }
}

// Per bucket: weighted-degree histogram -> dinv, then fold dinv into this
// bucket's xw2 rows (contiguous 64KB slab, coalesced).  Must precede any
// cross-bucket xw2 gather.
__global__ __launch_bounds__(512) void k_scale(const int* __restrict__ gcur,
                                               const uint2* __restrict__ part,
                                               float* __restrict__ dinv,
                                               __half* __restrict__ xw2, int n) {
    __shared__ float wsum[NPB];
    int b = blockIdx.x;
    int t = threadIdx.x;          // blockDim == 512
    wsum[t] = 0.0f;
    __syncthreads();
    int beg = b * PCAP;
    int len = gcur[b * GPAD] - beg;
    if (len > PCAP) len = PCAP;
    for (int j = t; j < len; j += 512) {
        uint2 ed = part[beg + j];
        atomicAdd(&wsum[(ed.x >> 17) & (NPB - 1)], __uint_as_float(ed.y));
    }
    __syncthreads();
    float dval = rsqrtf(1.0f + wsum[t]);
    int node = (b << NPB_LOG) + t;
    if (node < n) dinv[node] = dval;
    __syncthreads();
    wsum[t] = dval;               // reuse as LDS dinv table
    __syncthreads();
    int node0 = b << NPB_LOG;
    int nrows = n - node0;
    if (nrows > NPB) nrows = NPB;
    if (nrows > 0) {
        uint2* xp = (uint2*)(xw2 + (size_t)node0 * 64);   // 16 uint2 per row
        int tot = nrows * 16;
        for (int j = t; j < tot; j += 512) {
            float d = wsum[j >> 4];
            uint2 u = xp[j];
            __half2* h = (__half2*)&u;
#pragma unroll
            for (int k = 0; k < 2; ++k) {
                float2 f = __half22float2(h[k]);
                h[k] = __floats2half2_rn(f.x * d, f.y * d);
            }
            xp[j] = u;
        }
    }
}

// Layer-1 direct aggregation from the coarse partition.  One block per
// bucket; full fp32 bucket accumulator in LDS (512 x 64 = 128KB).  Wave per
// edge-octet (edge descs are wave-uniform scalar loads); lane = feature;
// ds_add_f32 fire-and-forget into acc[dlow][lane] (conflict-free banks).
// Epilogue: g[i] = dinv[i] * sum_f relu(dinv_fold(inner)_f + b1_f) * W2_f.
#define AG1(EK) do { \
    float v = __half2float(xw2[(size_t)(EK.x & 0x1FFFF) * 64 + lane]); \
    atomicAdd(&acc[((EK.x >> 17) & (NPB - 1)) * 64 + lane], \
              __uint_as_float(EK.y) * v); } while (0)

__global__ __launch_bounds__(1024) void k_agg1d(const int* __restrict__ gcur,
                                                const uint2* __restrict__ part,
                                                const float* __restrict__ dinv,
                                                const __half* __restrict__ xw2,
                                                const float* __restrict__ b1,
                                                const float* __restrict__ W2,
                                                float* __restrict__ g, int n) {
    __shared__ float acc[NPB * 64];   // 128 KB
    int b = blockIdx.x;
    int t = threadIdx.x;              // blockDim == 1024 (16 waves)
    int lane = t & 63, wv = t >> 6;
    for (int j = t; j < NPB * 64; j += 1024) acc[j] = 0.0f;
    __syncthreads();
    int beg = b * PCAP;
    int len = gcur[b * GPAD] - beg;
    if (len > PCAP) len = PCAP;
    const uint2* __restrict__ ep = part + beg;
    int noct = len >> 3;
    for (int o = wv; o < noct; o += 16) {
        const uint2* e = ep + o * 8;
        uint2 e0 = e[0], e1 = e[1], e2 = e[2], e3 = e[3];
        uint2 e4 = e[4], e5 = e[5], e6 = e[6], e7 = e[7];
        AG1(e0); AG1(e1); AG1(e2); AG1(e3);
        AG1(e4); AG1(e5); AG1(e6); AG1(e7);
    }
    if (wv == 0) {                    // tail (<8 edges)
        for (int j = noct << 3; j < len; ++j) {
            uint2 e = ep[j];
            AG1(e);
        }
    }
    __syncthreads();
    // epilogue: wave per node
    float bb = b1[lane], ww = W2[lane];
    int node0 = b << NPB_LOG;
    for (int nd = wv; nd < NPB; nd += 16) {
        int gn = node0 + nd;
        if (gn >= n) break;           // monotone in nd
        float inner = acc[nd * 64 + lane]
                    + __half2float(xw2[(size_t)gn * 64 + lane]);  // self-loop
        float di = dinv[gn];
        float h = fmaxf(di * inner + bb, 0.0f) * ww;
        for (int off = 32; off; off >>= 1) h += __shfl_down(h, off, 64);
        if (lane == 0) g[gn] = di * h;
    }
}

// Layer-2 direct aggregation: acc2[512] scalars in LDS; g gathers are 4B
// L2-resident.  out[i] = b2 + dinv[i] * ( g[i] + sum_e ew * g[s] ).
__global__ __launch_bounds__(1024) void k_agg2d(const int* __restrict__ gcur,
                                                const uint2* __restrict__ part,
                                                const float* __restrict__ dinv,
                                                const float* __restrict__ g,
                                                const float* __restrict__ b2,
                                                float* __restrict__ out, int n) {
    __shared__ float acc2[NPB];
    int b = blockIdx.x;
    int t = threadIdx.x;              // blockDim == 1024
    if (t < NPB) acc2[t] = 0.0f;
    __syncthreads();
    int beg = b * PCAP;
    int len = gcur[b * GPAD] - beg;
    if (len > PCAP) len = PCAP;
    const uint2* __restrict__ ep = part + beg;
    for (int j = t; j < len; j += 1024) {
        uint2 e = ep[j];
        atomicAdd(&acc2[(e.x >> 17) & (NPB - 1)],
                  __uint_as_float(e.y) * g[e.x & 0x1FFFF]);
    }
    __syncthreads();
    int node = (b << NPB_LOG) + t;
    if (t < NPB && node < n)
        out[node] = b2[0] + dinv[node] * (g[node] + acc2[t]);
}

extern "C" void kernel_launch(void* const* d_in, const int* in_sizes, int n_in,
                              void* d_out, int out_size, void* d_ws, size_t ws_size,
                              hipStream_t stream) {
    const float* x  = (const float*)d_in[0];
    const int*   ei = (const int*)  d_in[1];
    const float* ea = (const float*)d_in[2];
    const float* W1 = (const float*)d_in[3];
    const float* b1 = (const float*)d_in[4];
    const float* W2 = (const float*)d_in[5];
    const float* b2 = (const float*)d_in[6];
    float* out = (float*)d_out;

    int n = in_sizes[0] / 128;
    int E = in_sizes[1] / 2;
    const int* src = ei;
    const int* dst = ei + E;
    int npart = (n + NPB - 1) >> NPB_LOG;      // 196 for n=100k
    int nA = (E + NEDG - 1) / NEDG;            // 391 binning blocks
    int nG = (n + 63) / 64;                    // 1563 gemm blocks

    // ws layout (4B words):
    //   gcur[256*GPAD] | part[psz*2] | xw2[32n] | dinv[n] | g[n]   (~41 MB)
    int*    ws       = (int*)d_ws;
    int*    gcur     = ws;
    uint2*  part     = (uint2*)(ws + 256 * GPAD);
    size_t  psz      = (size_t)npart * PCAP;
    __half* xw2      = (__half*)(ws + 256 * GPAD + psz * 2);
    float*  dinv     = (float*)(ws + 256 * GPAD + psz * 2 + (size_t)32 * n);
    float*  g        = dinv + n;

    k_initcur  <<<1, 256, 0, stream>>>(gcur, npart);
    k_binA_gemm<<<nA + nG, 256, 0, stream>>>(src, dst, ea, gcur, part,
                                             x, W1, xw2, E, npart, nA, n);
    k_scale    <<<npart, 512, 0, stream>>>(gcur, part, dinv, xw2, n);
    k_agg1d    <<<npart, 1024, 0, stream>>>(gcur, part, dinv, xw2, b1, W2, g, n);
    k_agg2d    <<<npart, 1024, 0, stream>>>(gcur, part, dinv, g, b2, out, n);
}

// Round 11
// 316.984 us; speedup vs baseline: 5.0540x; 5.0540x over previous
//
#include <hip/hip_runtime.h>
#include <hip/hip_fp16.h>

// ---------------------------------------------------------------------------
// 2-layer GCN, fp32 in/out.  out = b2 + A_hat( relu( A_hat(x@W1) + b1 ) @ W2 )
// A_hat = D^-1/2 (A + I) D^-1/2.
// Round 19: revert to R16 (best verified 317.1us) after R17 fusion (+2.4,
// LDS-union capped occupancy) and R18 direct-agg (4.3x regression, gather
// MLP comes from wave count) both failed.  ONE change vs R16: NEDG 8192->5120
// so binA's LDS drops 75KB->48KB -> 3 blocks/CU (was 2), 625 blocks.
// Disambiguates binA's ~72us: latency-bound (-> ~55us) vs LDS-pipe-bound
// (-> unchanged, structural floor established).
// ---------------------------------------------------------------------------

#define NPB_LOG 9
#define NPB     512                  // nodes per coarse bucket
#define PCAP    17408                // mean 16384 + 8 sigma (P_ovf ~1e-13)
#define NEDG    5120                 // edges per binA block (48KB -> 3 blk/CU)
#define GPAD    16                   // gcur stride in ints (64B line)

typedef _Float16 f16x8 __attribute__((ext_vector_type(8)));
typedef float    f32x4 __attribute__((ext_vector_type(4)));

__global__ void k_initcur(int* __restrict__ gcur, int npart) {
    int i = blockIdx.x * blockDim.x + threadIdx.x;
    if (i < npart) gcur[i * GPAD] = i * PCAP;
}

// Bin edges into npart (<=256) partitions by dst>>9, LDS-staged so global
// writes are bucket-contiguous runs.
__global__ __launch_bounds__(256) void k_binA(const int* __restrict__ src,
                                              const int* __restrict__ dst,
                                              const float* __restrict__ ea,
                                              int* __restrict__ gcur,
                                              uint2* __restrict__ part,
                                              int E, int npart) {
    __shared__ uint2 stag[NEDG];             // 40 KB staging, bucket-sorted
    __shared__ unsigned char stagb[NEDG];    // 5 KB bucket id per slot
    __shared__ int hist[256];                // histogram, then cursor
    __shared__ int lofs[256];                // exclusive block-local offsets
    __shared__ int base[256];                // reserved global base per bucket
    int t = threadIdx.x;
    int c0 = blockIdx.x * NEDG;
    hist[t] = 0;
    __syncthreads();
    // pass 1: histogram
    for (int j = t; j < NEDG; j += 256) {
        int e = c0 + j;
        if (e < E) atomicAdd(&hist[dst[e] >> NPB_LOG], 1);
    }
    __syncthreads();
    // Kogge-Stone scan over 256 entries -> exclusive offsets; reserve global
    int v = hist[t];
    lofs[t] = v;
    __syncthreads();
    for (int off = 1; off < 256; off <<= 1) {
        int u = (t >= off) ? lofs[t - off] : 0;
        __syncthreads();
        lofs[t] += u;
        __syncthreads();
    }
    int excl = lofs[t] - v;
    if (t < npart && v > 0) base[t] = atomicAdd(&gcur[t * GPAD], v);
    __syncthreads();
    lofs[t] = excl;
    hist[t] = excl;               // reuse as intra-block scatter cursor
    __syncthreads();
    // pass 2: scatter into LDS staging in bucket order
    for (int j = t; j < NEDG; j += 256) {
        int e = c0 + j;
        if (e < E) {
            int d = dst[e];
            int b = d >> NPB_LOG;
            int p = atomicAdd(&hist[b], 1);
            stag[p]  = make_uint2((uint)src[e] | ((uint)(d & (NPB - 1)) << 17),
                                  __float_as_uint(ea[e]));
            stagb[p] = (unsigned char)b;
        }
    }
    __syncthreads();
    // pass 3: flush — consecutive slots in a bucket -> consecutive global addrs
    int nvalid = min(NEDG, E - c0);
    for (int j = t; j < nvalid; j += 256) {
        int b = stagb[j];
        int gp = base[b] + (j - lofs[b]);
        if (gp < (b + 1) * PCAP) part[gp] = stag[j];
    }
}

// Phase B: one block per bucket.  Exact counting sort into ecsr + dinv + rows.
// Bucket edges staged once into LDS (139KB, occupancy-free at 196 blocks);
// pass-2 scatter reads LDS instead of re-reading part via L2.
__global__ __launch_bounds__(512) void k_binB(const int* __restrict__ gcur,
                                              const uint2* __restrict__ part,
                                              int2* __restrict__ ecsr,
                                              int2* __restrict__ rowdesc,
                                              float* __restrict__ dinv, int n) {
    __shared__ uint2 stag[PCAP];  // 139 KB bucket staging
    __shared__ int   cnt[NPB];
    __shared__ float wsum[NPB];
    __shared__ int   cur[NPB];
    __shared__ int   wsums[8];
    int b = blockIdx.x;
    int t = threadIdx.x;          // blockDim == NPB == 512
    int lane = t & 63, wv = t >> 6;
    cnt[t] = 0; wsum[t] = 0.0f;
    __syncthreads();
    int beg = b * PCAP;
    int len = gcur[b * GPAD] - beg;
    if (len > PCAP) len = PCAP;
    // pass 1: stage to LDS + histogram + weighted degree (from registers)
    for (int j = t; j < len; j += NPB) {
        uint2 ed = part[beg + j];
        stag[j] = ed;
        int dlow = (ed.x >> 17) & (NPB - 1);
        atomicAdd(&cnt[dlow], 1);
        atomicAdd(&wsum[dlow], __uint_as_float(ed.y));
    }
    __syncthreads();
    // shfl-based exclusive scan of cnt across 512 threads (8 waves)
    int v = cnt[t];
    int s = v;
    for (int off = 1; off < 64; off <<= 1) {
        int u = __shfl_up(s, off, 64);
        if (lane >= off) s += u;
    }
    if (lane == 63) wsums[wv] = s;
    __syncthreads();
    if (t < 64) {
        int x = (t < 8) ? wsums[t] : 0;
        for (int off = 1; off < 8; off <<= 1) {
            int u = __shfl_up(x, off, 64);
            if (lane >= off) x += u;
        }
        if (t < 8) wsums[t] = x;    // inclusive wave sums
    }
    __syncthreads();
    int excl = s - v + (wv > 0 ? wsums[wv - 1] : 0);
    cur[t] = excl;
    int node = (b << NPB_LOG) + t;
    if (node < n) {
        rowdesc[node] = make_int2(beg + excl, v);
        dinv[node]    = rsqrtf(1.0f + wsum[t]);
    }
    __syncthreads();
    // pass 2: scatter into exact rows, reading staged edges from LDS
    for (int j = t; j < len; j += NPB) {
        uint2 ed = stag[j];
        int dlow = (ed.x >> 17) & (NPB - 1);
        int p = atomicAdd(&cur[dlow], 1);
        ecsr[beg + p] = make_int2((int)(ed.x & 0x1FFFF), (int)ed.y);
    }
}

// MFMA gemm: xw2[n,64] = fp16( dinv[row] * (x[n,128] @ W1[128,64]) ).
#define XPAD 136
__global__ __launch_bounds__(256) void k_gemm1m(const float* __restrict__ x,
                                                const float* __restrict__ W1,
                                                const float* __restrict__ dinv,
                                                __half* __restrict__ xw2, int n) {
    __shared__ __align__(16) _Float16 xs[64 * XPAD];
    __shared__ __align__(16) _Float16 wt[64 * XPAD];
    int tid = threadIdx.x;
    int row0 = blockIdx.x * 64;
    for (int i = tid; i < 64 * 32; i += 256) {
        int r = i >> 5, k4 = i & 31;
        float4 f = make_float4(0.f, 0.f, 0.f, 0.f);
        int gr = row0 + r;
        if (gr < n) f = ((const float4*)x)[(size_t)gr * 32 + k4];
        union { _Float16 h[4]; uint2 u; } tmp;
        tmp.h[0] = (_Float16)f.x; tmp.h[1] = (_Float16)f.y;
        tmp.h[2] = (_Float16)f.z; tmp.h[3] = (_Float16)f.w;
        *(uint2*)&xs[r * XPAD + k4 * 4] = tmp.u;
    }
    for (int i = tid; i < 128 * 64; i += 256) {
        int k = i >> 6, nn = i & 63;
        wt[nn * XPAD + k] = (_Float16)W1[i];
    }
    __syncthreads();

    int strip = tid >> 6;
    int lane  = tid & 63;
    int quad  = lane >> 4;
    int m     = lane & 15;
    f32x4 acc[4] = {{0,0,0,0},{0,0,0,0},{0,0,0,0},{0,0,0,0}};
#pragma unroll
    for (int kc = 0; kc < 4; ++kc) {
        f16x8 a = *(const f16x8*)&xs[(strip * 16 + m) * XPAD + kc * 32 + quad * 8];
#pragma unroll
        for (int nt = 0; nt < 4; ++nt) {
            f16x8 b = *(const f16x8*)&wt[(nt * 16 + m) * XPAD + kc * 32 + quad * 8];
            acc[nt] = __builtin_amdgcn_mfma_f32_16x16x32_f16(a, b, acc[nt], 0, 0, 0);
        }
    }
    float dv[4];
#pragma unroll
    for (int reg = 0; reg < 4; ++reg) {
        int gr = row0 + strip * 16 + quad * 4 + reg;
        dv[reg] = (gr < n) ? dinv[gr] : 0.0f;
    }
#pragma unroll
    for (int nt = 0; nt < 4; ++nt) {
#pragma unroll
        for (int reg = 0; reg < 4; ++reg) {
            int gr = row0 + strip * 16 + quad * 4 + reg;
            if (gr < n)
                xw2[(size_t)gr * 64 + nt * 16 + m] = __float2half(dv[reg] * acc[nt][reg]);
        }
    }
}

// Layer-1 aggregation fused with relu+b1+W2 dot.  Wave per node, lane=feature.
// inner = xw2[i,:] + sum_e ew * xw2[s,:]   (dinv[s] pre-folded into xw2)
// g[i]  = dinv[i] * sum_f relu(dinv[i]*inner_f + b1_f) * W2_f
// R9-verified schedule: scalar s_load descriptors, 8-wide unroll, 4-way acc.
__global__ __launch_bounds__(256) void k_agg1f(const int2* __restrict__ rowdesc,
                                               const int2* __restrict__ ecsr,
                                               const float* __restrict__ dinv,
                                               const __half* __restrict__ xw2,
                                               const float* __restrict__ b1,
                                               const float* __restrict__ W2,
                                               float* __restrict__ g, int n) {
    int i = blockIdx.x * 4 + (threadIdx.x >> 6);
    int lane = threadIdx.x & 63;
    if (i >= n) return;
    // Wave-uniform row descriptor -> SGPRs; edge loop uses scalar s_loads.
    int2 rd = rowdesc[i];
    int beg = __builtin_amdgcn_readfirstlane(rd.x);
    int len = __builtin_amdgcn_readfirstlane(rd.y);
    const int2* __restrict__ ep = ecsr + beg;

    float a0 = __half2float(xw2[(size_t)i * 64 + lane]);   // self-loop term
    float a1 = 0.0f, a2 = 0.0f, a3 = 0.0f;
    int j = 0;
    for (; j + 8 <= len; j += 8) {
        int2 e0 = ep[j + 0];
        int2 e1 = ep[j + 1];
        int2 e2 = ep[j + 2];
        int2 e3 = ep[j + 3];
        int2 e4 = ep[j + 4];
        int2 e5 = ep[j + 5];
        int2 e6 = ep[j + 6];
        int2 e7 = ep[j + 7];
        float v0 = __half2float(xw2[(size_t)(uint)e0.x * 64 + lane]);
        float v1 = __half2float(xw2[(size_t)(uint)e1.x * 64 + lane]);
        float v2 = __half2float(xw2[(size_t)(uint)e2.x * 64 + lane]);
        float v3 = __half2float(xw2[(size_t)(uint)e3.x * 64 + lane]);
        float v4 = __half2float(xw2[(size_t)(uint)e4.x * 64 + lane]);
        float v5 = __half2float(xw2[(size_t)(uint)e5.x * 64 + lane]);
        float v6 = __half2float(xw2[(size_t)(uint)e6.x * 64 + lane]);
        float v7 = __half2float(xw2[(size_t)(uint)e7.x * 64 + lane]);
        a0 += __int_as_float(e0.y) * v0;
        a1 += __int_as_float(e1.y) * v1;
        a2 += __int_as_float(e2.y) * v2;
        a3 += __int_as_float(e3.y) * v3;
        a0 += __int_as_float(e4.y) * v4;
        a1 += __int_as_float(e5.y) * v5;
        a2 += __int_as_float(e6.y) * v6;
        a3 += __int_as_float(e7.y) * v7;
    }
    for (; j < len; ++j) {
        int2 e = ep[j];
        a0 += __int_as_float(e.y) * __half2float(xw2[(size_t)(uint)e.x * 64 + lane]);
    }
    float acc = (a0 + a1) + (a2 + a3);
    float di = dinv[i];
    float h = fmaxf(di * acc + b1[lane], 0.0f) * W2[lane];
    for (int off = 32; off; off >>= 1) h += __shfl_down(h, off, 64);
    if (lane == 0) g[i] = di * h;
}

// Layer-2 (scalar): out[i] = b2 + dinv[i] * ( g[i] + sum_e ew * g[s] )
__global__ __launch_bounds__(256) void k_agg2(const int2* __restrict__ rowdesc,
                                              const int2* __restrict__ ecsr,
                                              const float* __restrict__ dinv,
                                              const float* __restrict__ g,
                                              const float* __restrict__ b2,
                                              float* __restrict__ out, int n) {
    int i = blockIdx.x * 4 + (threadIdx.x >> 6);
    int lane = threadIdx.x & 63;
    if (i >= n) return;
    int2 rd = rowdesc[i];
    int beg = __builtin_amdgcn_readfirstlane(rd.x);
    int len = __builtin_amdgcn_readfirstlane(rd.y);
    const int2* __restrict__ ep = ecsr + beg;
    float p = 0.0f;
    for (int j = lane; j < len; j += 64) {
        int2 ed = ep[j];
        p += __int_as_float(ed.y) * g[ed.x];
    }
    for (int off = 32; off; off >>= 1) p += __shfl_down(p, off, 64);
    if (lane == 0) out[i] = b2[0] + dinv[i] * (g[i] + p);
}

extern "C" void kernel_launch(void* const* d_in, const int* in_sizes, int n_in,
                              void* d_out, int out_size, void* d_ws, size_t ws_size,
                              hipStream_t stream) {
    const float* x  = (const float*)d_in[0];
    const int*   ei = (const int*)  d_in[1];
    const float* ea = (const float*)d_in[2];
    const float* W1 = (const float*)d_in[3];
    const float* b1 = (const float*)d_in[4];
    const float* W2 = (const float*)d_in[5];
    const float* b2 = (const float*)d_in[6];
    float* out = (float*)d_out;

    int n = in_sizes[0] / 128;
    int E = in_sizes[1] / 2;
    const int* src = ei;
    const int* dst = ei + E;
    int npart = (n + NPB - 1) >> NPB_LOG;      // 196 for n=100k

    // ws layout (4B words):
    //   gcur[256*GPAD] | part[npart*PCAP*2] (xw2 fp16[64n] overlays after
    //   binB) | ecsr[npart*PCAP*2] | rowdesc[2n] | dinv[n] | g[n]
    int*    ws       = (int*)d_ws;
    int*    gcur     = ws;
    uint2*  part     = (uint2*)(ws + 256 * GPAD);
    __half* xw2      = (__half*)part;          // overlay: 128n bytes <= part bytes
    size_t  psz      = (size_t)npart * PCAP;
    int2*   ecsr     = (int2*)(ws + 256 * GPAD + psz * 2);
    int2*   rowdesc  = (int2*)(ws + 256 * GPAD + psz * 4);
    float*  dinv     = (float*)(ws + 256 * GPAD + psz * 4 + (size_t)2 * n);
    float*  g        = dinv + n;

    k_initcur<<<1, 256, 0, stream>>>(gcur, npart);
    k_binA  <<<(E + NEDG - 1) / NEDG, 256, 0, stream>>>(src, dst, ea, gcur, part, E, npart);
    k_binB  <<<npart, NPB, 0, stream>>>(gcur, part, ecsr, rowdesc, dinv, n);
    k_gemm1m<<<(n + 63) / 64, 256, 0, stream>>>(x, W1, dinv, xw2, n);
    k_agg1f <<<(n + 3) / 4, 256, 0, stream>>>(rowdesc, ecsr, dinv, xw2, b1, W2, g, n);
    k_agg2  <<<(n + 3) / 4, 256, 0, stream>>>(rowdesc, ecsr, dinv, g, b2, out, n);
}